// Round 8
// baseline (397.959 us; speedup 1.0000x reference)
//
#include <hip/hip_runtime.h>
#include <hip/hip_bf16.h>
#include <math.h>

// Problem constants (from reference)
#define N_HEADN 50000
#define N_TAILN 50000
#define NE      800000
#define F_IN    256
#define HH      4
#define HD      256   // H*D
#define FE      64
#define N_ETYPES 5
#define NEG_SLOPE 0.2f
#define NB_SCAN ((N_HEADN + 255) / 256)        // 196
#define NB_CVT  ((N_TAILN * F_IN) / (256 * 16)) // 3125
#define NB_HIST (NE / 256)                      // 3125
#define NB_HD   (N_HEADN / 4)                   // 12500 head_dot blocks
#define NT_PROJ (N_TAILN / 16)                  // 3125 row-tiles (exact)
#define NB_PROJ 256                             // 1 block per CU, grid-stride tiles

typedef __attribute__((ext_vector_type(8))) short bf16x8;
typedef __attribute__((ext_vector_type(4))) float f32x4;
typedef __attribute__((ext_vector_type(4))) unsigned u32x4;

// bf16 <-> fp32 (RNE), bit-level
static __device__ __forceinline__ unsigned short f2bf(float f) {
    unsigned u = __float_as_uint(f);
    return (unsigned short)((u + 0x7FFF + ((u >> 16) & 1)) >> 16);
}
static __device__ __forceinline__ float bf2f(unsigned short u) {
    return __uint_as_float((unsigned)u << 16);
}

// ---------------------------------------------------------------------------
// K_prep (fused):
//   blocks 0..NB_HIST-1                : histogram of head indices (counts
//                                        pre-zeroed by memsetAsync)
//   blocks NB_HIST..+NB_CVT-1          : Xb = bf16(X_tail) streaming cvt (nt)
//   block  NB_HIST+NB_CVT              : waT[h][k]
//   block  NB_HIST+NB_CVT+1            : he[ty][h]
//   blocks NB_HIST+NB_CVT+2 ..+257     : Wt[n][k] = bf16(W[k][n])
// ---------------------------------------------------------------------------
__global__ __launch_bounds__(256) void prep_kernel(const int* __restrict__ head,
                                                   int* __restrict__ counts,
                                                   const float* __restrict__ X,
                                                   unsigned short* __restrict__ Xb,
                                                   const float* __restrict__ W,
                                                   const float* __restrict__ a_l,
                                                   const float* __restrict__ W_e,
                                                   const float* __restrict__ a_e,
                                                   const float* __restrict__ edge_emb,
                                                   float* __restrict__ waT,
                                                   float* __restrict__ heo,
                                                   short* __restrict__ Wt) {
    const int b = blockIdx.x;
    if (b < NB_HIST) {
        int e = b * 256 + threadIdx.x;   // NE % 256 == 0
        atomicAdd(&counts[__builtin_nontemporal_load(&head[e])], 1);
    } else if (b < NB_HIST + NB_CVT) {
        size_t t = (size_t)(b - NB_HIST) * 256 + threadIdx.x;
        const f32x4* xp = (const f32x4*)X + t * 4;
        f32x4 v0 = __builtin_nontemporal_load(xp + 0);
        f32x4 v1 = __builtin_nontemporal_load(xp + 1);
        f32x4 v2 = __builtin_nontemporal_load(xp + 2);
        f32x4 v3 = __builtin_nontemporal_load(xp + 3);
        bf16x8 o0, o1;
        o0[0] = (short)f2bf(v0[0]); o0[1] = (short)f2bf(v0[1]);
        o0[2] = (short)f2bf(v0[2]); o0[3] = (short)f2bf(v0[3]);
        o0[4] = (short)f2bf(v1[0]); o0[5] = (short)f2bf(v1[1]);
        o0[6] = (short)f2bf(v1[2]); o0[7] = (short)f2bf(v1[3]);
        o1[0] = (short)f2bf(v2[0]); o1[1] = (short)f2bf(v2[1]);
        o1[2] = (short)f2bf(v2[2]); o1[3] = (short)f2bf(v2[3]);
        o1[4] = (short)f2bf(v3[0]); o1[5] = (short)f2bf(v3[1]);
        o1[6] = (short)f2bf(v3[2]); o1[7] = (short)f2bf(v3[3]);
        bf16x8* op = (bf16x8*)(Xb + t * 16);
        __builtin_nontemporal_store(o0, op + 0);
        __builtin_nontemporal_store(o1, op + 1);
    } else if (b == NB_HIST + NB_CVT) {
        int k = threadIdx.x;   // 0..255
        #pragma unroll
        for (int h = 0; h < HH; ++h) {
            float s = 0.f;
            for (int d = 0; d < 64; ++d) s += a_l[h * 64 + d] * W[(size_t)k * HD + h * 64 + d];
            waT[h * 256 + k] = s;
        }
    } else if (b == NB_HIST + NB_CVT + 1) {
        __shared__ float wae[FE][HH];
        int t = threadIdx.x;          // 256 threads = 64 k x 4 h
        int k = t >> 2, h = t & 3;
        float s = 0.f;
        for (int f = 0; f < 64; ++f) s += a_e[h * 64 + f] * W_e[(size_t)k * (FE * HH) + h * 64 + f];
        wae[k][h] = s;
        __syncthreads();
        if (t < N_ETYPES * HH) {
            int ty = t >> 2, hh = t & 3;
            float acc = 0.f;
            for (int kk = 0; kk < FE; ++kk) acc += edge_emb[ty * FE + kk] * wae[kk][hh];
            heo[ty * HH + hh] = acc;
        }
    } else {
        int n = b - (NB_HIST + NB_CVT + 2), k = threadIdx.x;
        Wt[(size_t)n * 256 + k] = (short)f2bf(W[(size_t)k * 256 + n]);
    }
}

// ---------------------------------------------------------------------------
// K_mid (fused): blocks 0..NB_SCAN-1  -> CSR scan with device arrive/spin
//                                        barrier (all 196 blocks co-residable;
//                                        head_dot blocks never wait, so slots
//                                        always free up -> no deadlock under
//                                        any dispatch order)
//                blocks NB_SCAN..      -> head_dot (hl thin GEMM)
// Replaces blocksum + rowstart + head_dot (3 dispatches -> 1).
// ---------------------------------------------------------------------------
__global__ __launch_bounds__(256) void mid_kernel(const int* __restrict__ counts,
                                                  int* __restrict__ blockSums,
                                                  int* __restrict__ scanflag,
                                                  int* __restrict__ row_start,
                                                  int* __restrict__ cursor,
                                                  const float* __restrict__ X,
                                                  const float* __restrict__ waT,
                                                  float* __restrict__ hl) {
    const int b = blockIdx.x;
    if (b < NB_SCAN) {
        __shared__ int s[256];
        __shared__ int bs[256];
        const int t = threadIdx.x;
        const int j = b * 256 + t;
        const int c = (j < N_HEADN) ? counts[j] : 0;
        // inclusive scan of this block's 256 counts
        s[t] = c;
        __syncthreads();
        for (int off = 1; off < 256; off <<= 1) {
            int u = (t >= off) ? s[t - off] : 0;
            __syncthreads();
            s[t] += u;
            __syncthreads();
        }
        // publish block total, arrive
        if (t == 0) {
            blockSums[b] = s[255];
            __threadfence();
            atomicAdd(scanflag, 1);
            while (atomicAdd(scanflag, 0) < NB_SCAN) { /* spin */ }
        }
        __syncthreads();
        __threadfence();
        // scan the 196 block totals (redundant per block, LDS)
        bs[t] = (t < NB_SCAN) ? blockSums[t] : 0;
        __syncthreads();
        for (int off = 1; off < 256; off <<= 1) {
            int u = (t >= off) ? bs[t - off] : 0;
            __syncthreads();
            bs[t] += u;
            __syncthreads();
        }
        const int blockOffV = (b == 0) ? 0 : bs[b - 1];
        int excl = blockOffV + s[t] - c;
        if (j < N_HEADN) {
            row_start[j] = excl;
            cursor[j]    = excl;
            if (j == N_HEADN - 1) row_start[N_HEADN] = excl + c;
        }
    } else {
        // head_dot: hl = X_head @ waT^T, one wave per row
        const int wave = threadIdx.x >> 6;
        const int lane = threadIdx.x & 63;
        const int n = (b - NB_SCAN) * 4 + wave;   // N_HEADN % 4 == 0
        f32x4 x = __builtin_nontemporal_load((const f32x4*)(X + (size_t)n * F_IN) + lane);
        float p[HH];
        #pragma unroll
        for (int h = 0; h < HH; ++h) {
            f32x4 w = *((const f32x4*)(waT + h * 256) + lane);
            p[h] = x[0] * w[0] + x[1] * w[1] + x[2] * w[2] + x[3] * w[3];
        }
        #pragma unroll
        for (int off = 1; off < 64; off <<= 1) {
            #pragma unroll
            for (int h = 0; h < HH; ++h) p[h] += __shfl_xor(p[h], off);
        }
        if (lane < HH) hl[(size_t)n * HH + lane] = p[lane];
    }
}

// ---------------------------------------------------------------------------
// K3b v4: h_tail = Xb(bf16) @ W, swapped-operand MFMA (D = Wt·Xb^T), with
// Wt staged ONCE per block in LDS (128 KB, 1 block/CU, grid=256).
// (round-7-verified: fixed the L1-MSHR serialization of in-loop Wt loads)
// ---------------------------------------------------------------------------
static __device__ __forceinline__ void proj_load_xf(const unsigned short* __restrict__ Xb,
                                                    int tile, int l15, int quad,
                                                    bf16x8* xf) {
    const unsigned short* xbase = Xb + (size_t)(tile * 16 + l15) * F_IN + quad * 8;
    #pragma unroll
    for (int kk = 0; kk < 8; ++kk)
        xf[kk] = __builtin_nontemporal_load((const bf16x8*)(xbase + kk * 32));
}

static __device__ __forceinline__ void proj_compute(const char* __restrict__ smem,
                                                    const float* __restrict__ a,
                                                    unsigned short* __restrict__ h_out,
                                                    float* __restrict__ hr,
                                                    int tile, int h, int lane,
                                                    const bf16x8* xf) {
    const int quad = lane >> 4;
    const int l15  = lane & 15;
    f32x4 acc[4];
    #pragma unroll
    for (int ct = 0; ct < 4; ++ct) acc[ct] = (f32x4){0.f, 0.f, 0.f, 0.f};

    int colb[4], sw[4];
    #pragma unroll
    for (int ct = 0; ct < 4; ++ct) {
        int col = h * 64 + ct * 16 + l15;
        colb[ct] = col * 512;
        sw[ct]   = col & 31;
    }

    #pragma unroll
    for (int kk = 0; kk < 8; ++kk) {
        #pragma unroll
        for (int ct = 0; ct < 4; ++ct) {
            int addr = colb[ct] + ((((quad + kk * 4)) ^ sw[ct]) << 4);
            bf16x8 wf = *(const bf16x8*)(smem + addr);
            acc[ct] = __builtin_amdgcn_mfma_f32_16x16x32_bf16(wf, xf[kk], acc[ct], 0, 0, 0);
        }
    }

    const int row = tile * 16 + l15;
    float hp = 0.f;
    #pragma unroll
    for (int ct = 0; ct < 4; ++ct) {
        float4 av = *(const float4*)(a + h * 64 + ct * 16 + quad * 4);
        hp += av.x * acc[ct][0] + av.y * acc[ct][1]
            + av.z * acc[ct][2] + av.w * acc[ct][3];
        ushort4 pk;
        pk.x = f2bf(acc[ct][0]); pk.y = f2bf(acc[ct][1]);
        pk.z = f2bf(acc[ct][2]); pk.w = f2bf(acc[ct][3]);
        *(ushort4*)(h_out + (size_t)row * HD + h * 64 + ct * 16 + quad * 4) = pk;
    }
    hp += __shfl_xor(hp, 16);
    hp += __shfl_xor(hp, 32);
    if (lane < 16) hr[(size_t)row * HH + h] = hp;
}

__global__ __launch_bounds__(256) void proj_mfma_kernel(const unsigned short* __restrict__ Xb,
                                                        const short* __restrict__ Wt,
                                                        const float* __restrict__ a,
                                                        unsigned short* __restrict__ h_out,
                                                        float* __restrict__ hr) {
    extern __shared__ char smem[];       // 128 KB: 256 cols x 512 B, XOR-swizzled
    const int h    = threadIdx.x >> 6;   // wave = head 0..3
    const int lane = threadIdx.x & 63;
    const int l15  = lane & 15;
    const int quad = lane >> 4;

    int tile = blockIdx.x;
    bf16x8 xfA[8], xfB[8];
    if (tile < NT_PROJ) proj_load_xf(Xb, tile, l15, quad, xfA);

    {
        const int t = threadIdx.x;
        #pragma unroll
        for (int i = 0; i < 32; ++i) {
            int m = i * 256 + t;                 // 16B-chunk linear index
            bf16x8 v = *(const bf16x8*)(Wt + (size_t)m * 8);
            int col = m >> 5;
            int c   = m & 31;
            *(bf16x8*)(smem + col * 512 + ((c ^ (col & 31)) << 4)) = v;
        }
    }
    __syncthreads();

    while (tile < NT_PROJ) {
        int nxt = tile + NB_PROJ;
        if (nxt < NT_PROJ) proj_load_xf(Xb, nxt, l15, quad, xfB);
        proj_compute(smem, a, h_out, hr, tile, h, lane, xfA);
        tile = nxt;
        if (tile >= NT_PROJ) break;
        nxt = tile + NB_PROJ;
        if (nxt < NT_PROJ) proj_load_xf(Xb, nxt, l15, quad, xfA);
        proj_compute(smem, a, h_out, hr, tile, h, lane, xfB);
        tile = nxt;
    }
}

// ---------------------------------------------------------------------------
// K4: scatter each edge into its CSR slot; compute ex = exp(leaky(hl+hr+he))
// for all 4 heads here (edge-parallel). packed[pos] = tail; exE[pos][h] = ex.
// Streaming writes nontemporal (read back only in agg; keep L2 for gathers).
// ---------------------------------------------------------------------------
__global__ void scatter_kernel(const int* __restrict__ head, const int* __restrict__ tail,
                               const int* __restrict__ etype,
                               const float* __restrict__ hl, const float* __restrict__ hr,
                               const float* __restrict__ he,
                               int* __restrict__ cursor, int* __restrict__ packed,
                               float* __restrict__ exE) {
    int e = blockIdx.x * 256 + threadIdx.x;   // NE % 256 == 0
    int h0 = __builtin_nontemporal_load(&head[e]);
    int tl = __builtin_nontemporal_load(&tail[e]);
    int ty = __builtin_nontemporal_load(&etype[e]);
    float4 L = *(const float4*)(hl + (size_t)h0 * HH);
    float4 R = *(const float4*)(hr + (size_t)tl * HH);
    float4 T = *(const float4*)(he + ty * HH);
    float s0 = L.x + R.x + T.x;
    float s1 = L.y + R.y + T.y;
    float s2 = L.z + R.z + T.z;
    float s3 = L.w + R.w + T.w;
    s0 = (s0 > 0.f) ? s0 : NEG_SLOPE * s0;
    s1 = (s1 > 0.f) ? s1 : NEG_SLOPE * s1;
    s2 = (s2 > 0.f) ? s2 : NEG_SLOPE * s2;
    s3 = (s3 > 0.f) ? s3 : NEG_SLOPE * s3;
    float w0 = __expf(s0), w1 = __expf(s1), w2 = __expf(s2), w3 = __expf(s3);
    int pos = atomicAdd(&cursor[h0], 1);
    packed[pos] = tl;
    f32x4 wv = (f32x4){w0, w1, w2, w3};
    __builtin_nontemporal_store(wv, (f32x4*)(exE + (size_t)pos * HH));
}

// ---------------------------------------------------------------------------
// K5: aggregation. One wave per head node. 2 edges/iteration, 32 lanes per
// edge, each lane one DENSE uint4 (16B) of the 512B h_tail row.
// Streaming accesses (packed/exE loads, out stores) are NONTEMPORAL so L2
// stays dedicated to the random h_tail gather working set (25.6 MB).
// ---------------------------------------------------------------------------
__global__ __launch_bounds__(256) void agg_kernel(const int* __restrict__ row_start,
                                                  const int* __restrict__ packed,
                                                  const float* __restrict__ exE,
                                                  const unsigned short* __restrict__ h_tail, // bf16
                                                  float* __restrict__ out) {
    const int wave = threadIdx.x >> 6;
    const int lane = threadIdx.x & 63;
    const int n = blockIdx.x * 4 + wave;      // N_HEADN % 4 == 0
    const int s = row_start[n];
    const int e = row_start[n + 1];
    const int g = lane >> 5;      // edge sub-stream 0..1
    const int q = lane & 31;      // column chunk: cols 8q..8q+7
    const int h = q >> 3;         // attention head for these cols

    float acc[8];
    #pragma unroll
    for (int c = 0; c < 8; ++c) acc[c] = 0.f;
    float z = 0.f;

    for (int base = s; base < e; base += 64) {
        const int cnt = (e - base < 64) ? (e - base) : 64;
        int myidx = 0;
        if (base + lane < e) myidx = __builtin_nontemporal_load(&packed[base + lane]);
        #pragma unroll 8
        for (int i = 0; i < cnt; i += 2) {
            const int j = i + g;
            const int tl = __shfl(myidx, j);
            if (j < cnt) {
                const float w = __builtin_nontemporal_load(&exE[(size_t)(base + j) * HH + h]);
                u32x4 u = *(const u32x4*)(h_tail + (size_t)tl * HD + q * 8);
                #pragma unroll
                for (int d = 0; d < 4; ++d) {
                    unsigned uu = u[d];
                    acc[2 * d]     += w * __uint_as_float(uu << 16);
                    acc[2 * d + 1] += w * __uint_as_float(uu & 0xFFFF0000u);
                }
                z += w;
            }
        }
    }

    #pragma unroll
    for (int c = 0; c < 8; ++c) acc[c] += __shfl_xor(acc[c], 32);
    z += __shfl_xor(z, 32);

    f32x4 o;
    if (z > 0.f) {
        o[0] = acc[4 * g + 0] / z;
        o[1] = acc[4 * g + 1] / z;
        o[2] = acc[4 * g + 2] / z;
        o[3] = acc[4 * g + 3] / z;
        o[0] = (o[0] > 0.f) ? o[0] : expm1f(o[0]);
        o[1] = (o[1] > 0.f) ? o[1] : expm1f(o[1]);
        o[2] = (o[2] > 0.f) ? o[2] : expm1f(o[2]);
        o[3] = (o[3] > 0.f) ? o[3] : expm1f(o[3]);
    } else {
        o = (f32x4){0.f, 0.f, 0.f, 0.f};
    }
    __builtin_nontemporal_store(o, (f32x4*)(out + (size_t)n * HD) + (q * 2 + g));
}

// ---------------------------------------------------------------------------
extern "C" void kernel_launch(void* const* d_in, const int* in_sizes, int n_in,
                              void* d_out, int out_size, void* d_ws, size_t ws_size,
                              hipStream_t stream) {
    const float* head_feature = (const float*)d_in[0];
    const float* tail_feature = (const float*)d_in[1];
    const int*   edge_list    = (const int*)d_in[2];   // [2, E]
    const int*   tmp_edge     = (const int*)d_in[3];   // [E]
    const float* W            = (const float*)d_in[4];
    const float* W_e          = (const float*)d_in[5];
    const float* edge_emb     = (const float*)d_in[6];
    const float* a_l          = (const float*)d_in[7];
    const float* a_r          = (const float*)d_in[8];
    const float* a_e          = (const float*)d_in[9];
    const int* head_ind = edge_list;
    const int* tail_ind = edge_list + NE;

    // Workspace carve-up (~54 MB), 16B-aligned chunks first.
    // Xb (bf16 tail features, dead after proj) ALIASES exE+packed.
    char* ws = (char*)d_ws;
    unsigned short* h_tail = (unsigned short*)ws; ws += sizeof(unsigned short) * (size_t)N_TAILN * HD; // 25.6 MB
    unsigned short* Xb = (unsigned short*)ws;      // 25.6 MB region R
    float* exE    = (float*)(void*)Xb;                                          // alias: 12.8 MB
    int*   packed = (int*)(void*)((char*)(void*)Xb + sizeof(float) * (size_t)NE * HH); // alias: 3.2 MB
    ws += sizeof(unsigned short) * (size_t)N_TAILN * HD;
    short* Wt        = (short*)ws; ws += sizeof(short) * 256 * 256;              // 128 KB
    float* hl        = (float*)ws; ws += sizeof(float) * (size_t)N_HEADN * HH;   // 0.8 MB
    float* hr        = (float*)ws; ws += sizeof(float) * (size_t)N_TAILN * HH;   // 0.8 MB
    float* waT       = (float*)ws; ws += sizeof(float) * HH * 256;               // 4 KB
    float* he        = (float*)ws; ws += sizeof(float) * 32;                     // padded
    int*   counts    = (int*)ws;   ws += sizeof(int) * (size_t)N_HEADN;          // 0.2 MB
    int*   scanflag  = (int*)ws;   ws += sizeof(int) * 4;                        // barrier flag (zeroed with counts)
    int*   row_start = (int*)ws;   ws += sizeof(int) * (size_t)(N_HEADN + 4);    // 0.2 MB
    int*   cursor    = (int*)ws;   ws += sizeof(int) * (size_t)N_HEADN;          // 0.2 MB
    int*   blockSums = (int*)ws;   ws += sizeof(int) * 256;

    // zero counts AND scanflag in one contiguous memset
    hipMemsetAsync(counts, 0, sizeof(int) * ((size_t)N_HEADN + 4), stream);

    // fused prep: hist | Xb cvt | waT | he | Wt — one dispatch
    hipLaunchKernelGGL(prep_kernel, dim3(NB_HIST + NB_CVT + 258), dim3(256), 0, stream,
                       head_ind, counts, tail_feature, Xb,
                       W, a_l, W_e, a_e, edge_emb, waT, he, Wt);

    // fused mid: CSR scan (spin barrier) | head_dot — one dispatch
    hipLaunchKernelGGL(mid_kernel, dim3(NB_SCAN + NB_HD), dim3(256), 0, stream,
                       counts, blockSums, scanflag, row_start, cursor,
                       head_feature, waT, hl);

    // proj: 1 block/CU, 128 KB dynamic LDS (allow >64KB defensively)
    static bool lds_attr_set = false;
    if (!lds_attr_set) {
        hipFuncSetAttribute((const void*)proj_mfma_kernel,
                            hipFuncAttributeMaxDynamicSharedMemorySize, 131072);
        lds_attr_set = true;
    }
    hipLaunchKernelGGL(proj_mfma_kernel, dim3(NB_PROJ), dim3(256), 131072, stream,
                       Xb, Wt, a_r, h_tail, hr);

    hipLaunchKernelGGL(scatter_kernel, dim3(NE / 256), dim3(256), 0, stream,
                       head_ind, tail_ind, tmp_edge, hl, hr, he, cursor, packed, exE);

    hipLaunchKernelGGL(agg_kernel, dim3(N_HEADN / 4), dim3(256), 0, stream,
                       row_start, packed, exE, h_tail, (float*)d_out);
}